// Round 7
// baseline (3312.904 us; speedup 1.0000x reference)
//
#include <hip/hip_runtime.h>
#include <hip/hip_bf16.h>

using f32x4  = __attribute__((ext_vector_type(4))) float;
using bf16x8 = __attribute__((ext_vector_type(8))) __bf16;
using u64    = unsigned long long;
using u32    = unsigned int;

#define T_DIM 512
#define B_DIM 64
#define D_DIM 1024
#define H_DIM 1024
#define G_DIM 4096   // 4*H
#define NWG   128    // scan wgs: 4 row-groups x 32 unit-blocks
#define WGT   512    // threads per scan wg (8 waves)

// ---------------------------------------------------------------------------
// fp32 -> bf16 conversion (vectorized 8/thread)
// ---------------------------------------------------------------------------
__global__ void f32_to_bf16_kernel(const float* __restrict__ src,
                                   __bf16* __restrict__ dst, long n) {
    long i = ((long)blockIdx.x * blockDim.x + threadIdx.x) * 8;
    if (i + 8 <= n) {
        f32x4 a = *(const f32x4*)(src + i);
        f32x4 b = *(const f32x4*)(src + i + 4);
        bf16x8 o;
        o[0] = (__bf16)a[0]; o[1] = (__bf16)a[1];
        o[2] = (__bf16)a[2]; o[3] = (__bf16)a[3];
        o[4] = (__bf16)b[0]; o[5] = (__bf16)b[1];
        o[6] = (__bf16)b[2]; o[7] = (__bf16)b[3];
        *(bf16x8*)(dst + i) = o;
    }
}

// ---------------------------------------------------------------------------
// Phase 1: xg[M][4096] = A[M][1024](bf16) @ W[4096][1024]^T (bf16) + bias
// (unchanged)
// ---------------------------------------------------------------------------
#define BM 128
#define BN 128
#define BK 64

__global__ __launch_bounds__(256) void gemm_xg_kernel(
    const __bf16* __restrict__ A,    // [M][1024]
    const __bf16* __restrict__ W,    // [4096][1024]
    const float* __restrict__ bias,  // [4096]
    float* __restrict__ C,           // [M][4096]
    int M)
{
    (void)M;
    __shared__ __bf16 sA[BM * BK];
    __shared__ __bf16 sB[BN * BK];

    const int tid = threadIdx.x;
    const int wv  = tid >> 6;
    const int l   = tid & 63;
    const int wy  = wv >> 1, wx = wv & 1;
    const int bm  = blockIdx.y * BM;
    const int bn  = blockIdx.x * BN;
    const int n   = l & 15;
    const int q   = l >> 4;

    const int srow  = l >> 3;
    const int skoff = (l & 7) * 8;

    f32x4 acc[4][4];
    #pragma unroll
    for (int mt = 0; mt < 4; ++mt)
        #pragma unroll
        for (int nt = 0; nt < 4; ++nt)
            acc[mt][nt] = (f32x4){0.f, 0.f, 0.f, 0.f};

    for (int kt = 0; kt < D_DIM / BK; ++kt) {
        const int k0 = kt * BK;
        #pragma unroll
        for (int j = 0; j < 4; ++j) {
            const int rbase = (j * 4 + wv) * 8;
            const __bf16* ga = A + (long)(bm + rbase + srow) * D_DIM + k0 + skoff;
            const __bf16* gb = W + (long)(bn + rbase + srow) * D_DIM + k0 + skoff;
            __builtin_amdgcn_global_load_lds(
                (const __attribute__((address_space(1))) void*)ga,
                (__attribute__((address_space(3))) void*)(sA + rbase * BK), 16, 0, 0);
            __builtin_amdgcn_global_load_lds(
                (const __attribute__((address_space(1))) void*)gb,
                (__attribute__((address_space(3))) void*)(sB + rbase * BK), 16, 0, 0);
        }
        __syncthreads();

        #pragma unroll
        for (int ks = 0; ks < 2; ++ks) {
            bf16x8 af[4], bfr[4];
            #pragma unroll
            for (int mt = 0; mt < 4; ++mt) {
                int row = wy * 64 + mt * 16 + n;
                af[mt] = *(const bf16x8*)(sA + row * BK + ks * 32 + q * 8);
            }
            #pragma unroll
            for (int nt = 0; nt < 4; ++nt) {
                int col = wx * 64 + nt * 16 + n;
                bfr[nt] = *(const bf16x8*)(sB + col * BK + ks * 32 + q * 8);
            }
            #pragma unroll
            for (int mt = 0; mt < 4; ++mt)
                #pragma unroll
                for (int nt = 0; nt < 4; ++nt)
                    acc[mt][nt] = __builtin_amdgcn_mfma_f32_16x16x32_bf16(
                        af[mt], bfr[nt], acc[mt][nt], 0, 0, 0);
        }
        __syncthreads();
    }

    #pragma unroll
    for (int nt = 0; nt < 4; ++nt) {
        int col = bn + wx * 64 + nt * 16 + n;
        float b = bias[col];
        #pragma unroll
        for (int mt = 0; mt < 4; ++mt) {
            #pragma unroll
            for (int r = 0; r < 4; ++r) {
                int row = bm + wy * 64 + mt * 16 + q * 4 + r;
                C[(long)row * G_DIM + col] = acc[mt][nt][r] + b;
            }
        }
    }
}

// ---------------------------------------------------------------------------
// fast tanh via __expf. err ~1e-6, tol 1.5e-2.
// ---------------------------------------------------------------------------
__device__ __forceinline__ float fast_tanh(float x) {
    return 1.0f - 2.0f / (__expf(2.0f * x) + 1.0f);
}

// ---------------------------------------------------------------------------
// Phase 2: persistent scan, BARRIER-FREE epoch-tagged exchange (round 7).
// h is stored as u32 = (epoch16 << 16) | bf16(h): the data is its own flag.
// Consumer loads self-validate (high half == expected step tag) -> the whole
// {store -> vmcnt drain -> flag publish -> flag poll -> data load} chain
// (3 MALL RTs) collapses to {store -> load-until-tagged} (1 RT).
// Safety: each u32 self-tags (dword loads can't tear); 2 buffers + causality
// make WAR safe: a wg writes h(t+1) only after validating ALL of h(t), and
// every producer of h(t) wrote only after its h(t-1) reads completed (data
// dep), so epoch t+1 everywhere proves nobody still reads the buffer being
// overwritten. Zeroed buffers == epoch 0 == expected tag at gt=0. Epochs are
// continuous across chunk launches (<=512 < 2^16). Cooperative launch is
// kept for the co-residency guarantee (wgs spin on data; no barrier).
// Topology (round-5/6 proven): 128 wgs = 4 row-groups x 32 unit-blocks,
// 8 waves; wave wv owns units ublk*32+wv*4..+3 x all 4 gates; fragment-major
// LDS for conflict-free ds_read_b128; intra-wave gate exchange; shfl pack.
// ---------------------------------------------------------------------------
__global__ __launch_bounds__(WGT)
__attribute__((amdgpu_waves_per_eu(2, 2)))
void lstm_scan_kernel(
    const __bf16* __restrict__ Whb,   // [4096][1024] bf16
    const float* __restrict__ xg,     // [tc][64][4096] fp32 (chunk-local)
    const float* __restrict__ mask,   // [512][64]
    float* __restrict__ cst,          // [64][1024] fp32 chunk-boundary state
    u32* __restrict__ hbuf,           // [2][64][1024] u32 (epoch<<16 | bf16)
    float* __restrict__ out,          // [512][64][1024]
    int t0, int tc)
{
    __shared__ __align__(16) char shh[32768];   // h rows, fragment-major bf16
    __shared__ float sg[8][16 * 17];            // per-wave gate exchange

    const int tid  = threadIdx.x;
    const int wgid = blockIdx.x;
    const int rblk = wgid >> 5;          // row group 0..3 (rows rblk*16..+15)
    const int ublk = wgid & 31;          // unit block 0..31
    const int wv   = tid >> 6;
    const int l    = tid & 63;
    const int n    = l & 15;
    const int q    = l >> 4;

    // wave wv: units ublk*32 + wv*4..+3, all 4 gates (round-6 mapping)
    const int colg = ((n >> 2) << 10) + ublk * 32 + wv * 4 + (n & 3);

    bf16x8 breg[32];
    #pragma unroll
    for (int kk = 0; kk < 32; ++kk)
        breg[kk] = *(const bf16x8*)(Whb + (long)colg * H_DIM + kk * 32 + q * 8);

    // gate-phase ownership
    const int rloc = l >> 2;                   // 0..15
    const int ui   = l & 3;                    // 0..3
    const int grow = rblk * 16 + rloc;         // global batch row
    const int ucol = ublk * 32 + wv * 4 + ui;  // global hidden unit

    // staging geometry: wave wv covers rows (wv&1)*8 + (l>>3); lane handles
    // 8 x 16B pairs (4 tagged u32 = 4 units each) at pair index pb + 8s
    const int srow   = (wv & 1) * 8 + (l >> 3);        // wg-local row 0..15
    const int pb     = (wv >> 1) * 64 + (l & 7);       // 16B-pair base
    const long grow_s = (long)(rblk * 16 + srow);      // global staging row
    const int lds_off = ((l >> 1) & 3) * 256 + srow * 16 + (l & 1) * 8;

    float c_r, h_r;
    if (t0 == 0) { c_r = 0.0f; h_r = 0.0f; }
    else {
        c_r = cst[grow * H_DIM + ucol];
        h_r = out[((long)(t0 - 1) * B_DIM + grow) * H_DIM + ucol];
    }

    // prefetch xg/mask for t = 0
    float xc0, xc1, xc2, xc3, mkc;
    {
        const float* xr = xg + (long)grow * G_DIM + ucol;
        xc0 = xr[0]; xc1 = xr[H_DIM]; xc2 = xr[2 * H_DIM]; xc3 = xr[3 * H_DIM];
        mkc = mask[t0 * B_DIM + grow];
    }

    for (int t = 0; t < tc; ++t) {
        const int gt = t0 + t;
        const u32 ep  = (u32)gt & 0xFFFFu;
        const u32 ep1 = (u32)(gt + 1) & 0xFFFFu;
        const u64 et64 = ((u64)ep << 16) | ((u64)ep << 48);
        const u32* hr = hbuf + (long)(gt & 1) * (B_DIM * H_DIM);
        u32* hw = hbuf + (long)((gt + 1) & 1) * (B_DIM * H_DIM);

        // ---- load + self-validate (the data IS the flag) ----
        u64 lo[8], hi[8];
        #pragma unroll
        for (int s = 0; s < 8; ++s) {
            const u32* p = hr + grow_s * H_DIM + (pb + s * 8) * 4;
            lo[s] = __hip_atomic_load((const u64*)p,     __ATOMIC_RELAXED, __HIP_MEMORY_SCOPE_AGENT);
            hi[s] = __hip_atomic_load((const u64*)p + 1, __ATOMIC_RELAXED, __HIP_MEMORY_SCOPE_AGENT);
        }
        unsigned pend = 0xFFu;
        while (pend) {
            unsigned np = 0;
            #pragma unroll
            for (int s = 0; s < 8; ++s) {
                if (pend & (1u << s)) {
                    if ((((lo[s] ^ et64) | (hi[s] ^ et64)) & 0xFFFF0000FFFF0000ull) != 0ull) {
                        const u32* p = hr + grow_s * H_DIM + (pb + s * 8) * 4;
                        lo[s] = __hip_atomic_load((const u64*)p,     __ATOMIC_RELAXED, __HIP_MEMORY_SCOPE_AGENT);
                        hi[s] = __hip_atomic_load((const u64*)p + 1, __ATOMIC_RELAXED, __HIP_MEMORY_SCOPE_AGENT);
                        np |= 1u << s;
                    }
                }
            }
            pend = np;               // reloaded entries re-checked next round
            if (pend) __builtin_amdgcn_s_sleep(1);
        }

        // ---- strip tags, pack 4 bf16 -> 8B fragment-major LDS write ----
        #pragma unroll
        for (int s = 0; s < 8; ++s) {
            u32 w0 = (u32)lo[s], w1 = (u32)(lo[s] >> 32);
            u32 w2 = (u32)hi[s], w3 = (u32)(hi[s] >> 32);
            u64 pk = (u64)(unsigned short)w0 | ((u64)(unsigned short)w1 << 16)
                   | ((u64)(unsigned short)w2 << 32) | ((u64)(unsigned short)w3 << 48);
            const int kk = (wv >> 1) * 8 + s;
            *(u64*)(shh + kk * 1024 + lds_off) = pk;
        }
        __syncthreads();

        // ---- 32 MFMAs, full K, contiguous 1KB ds_read_b128 per fragment ----
        f32x4 ac0 = {0.f,0.f,0.f,0.f}, ac1 = {0.f,0.f,0.f,0.f};
        #pragma unroll
        for (int kk = 0; kk < 32; kk += 2) {
            bf16x8 f0 = *(const bf16x8*)(shh + (kk + 0) * 1024 + q * 256 + n * 16);
            bf16x8 f1 = *(const bf16x8*)(shh + (kk + 1) * 1024 + q * 256 + n * 16);
            ac0 = __builtin_amdgcn_mfma_f32_16x16x32_bf16(f0, breg[kk + 0], ac0, 0, 0, 0);
            ac1 = __builtin_amdgcn_mfma_f32_16x16x32_bf16(f1, breg[kk + 1], ac1, 0, 0, 0);
        }
        f32x4 acc = ac0 + ac1;

        // ---- intra-wave gate exchange (same-wave LDS, no barrier) ----
        #pragma unroll
        for (int r = 0; r < 4; ++r)
            sg[wv][(q * 4 + r) * 17 + n] = acc[r];

        float ig = xc0 + sg[wv][rloc * 17 + 0  + ui];
        float fg = xc1 + sg[wv][rloc * 17 + 4  + ui];
        float og = xc2 + sg[wv][rloc * 17 + 8  + ui];
        float gg = xc3 + sg[wv][rloc * 17 + 12 + ui];

        float i_s = 1.0f / (1.0f + __expf(-ig));
        float f_s = 1.0f / (1.0f + __expf(-fg));
        float o_s = 1.0f / (1.0f + __expf(-og));
        float g_t = fast_tanh(gg);
        float c_new = f_s * c_r + i_s * g_t;
        float h_new = o_s * fast_tanh(c_new);
        float c_f = mkc * c_new + (1.0f - mkc) * c_r;
        float h_f = mkc * h_new + (1.0f - mkc) * h_r;
        c_r = c_f;
        h_r = h_f;

        // ---- pack via shfl; TAGGED h stores FIRST (release other wgs) ----
        const int base = l & ~3;
        float v0 = __shfl(h_f, base + 0);
        float v1 = __shfl(h_f, base + 1);
        float v2 = __shfl(h_f, base + 2);
        float v3 = __shfl(h_f, base + 3);
        if (ui == 0) {
            u32 t0s = (ep1 << 16) | (u32)__builtin_bit_cast(unsigned short, (__bf16)v0);
            u32 t1s = (ep1 << 16) | (u32)__builtin_bit_cast(unsigned short, (__bf16)v1);
            u32 t2s = (ep1 << 16) | (u32)__builtin_bit_cast(unsigned short, (__bf16)v2);
            u32 t3s = (ep1 << 16) | (u32)__builtin_bit_cast(unsigned short, (__bf16)v3);
            u64 pk0 = (u64)t0s | ((u64)t1s << 32);
            u64 pk1 = (u64)t2s | ((u64)t3s << 32);
            u64* dp = (u64*)(hw + (long)grow * H_DIM + ublk * 32 + wv * 4);
            __hip_atomic_store(dp,     pk0, __ATOMIC_RELAXED, __HIP_MEMORY_SCOPE_AGENT);
            __hip_atomic_store(dp + 1, pk1, __ATOMIC_RELAXED, __HIP_MEMORY_SCOPE_AGENT);
            f32x4 ov = {v0, v1, v2, v3};
            *(f32x4*)(out + ((long)gt * B_DIM + grow) * H_DIM + ublk * 32 + wv * 4) = ov;
        }

        if (t == tc - 1) cst[grow * H_DIM + ucol] = c_f;

        // prefetch next step's xg/mask
        if (t + 1 < tc) {
            const float* xr = xg + ((long)(t + 1) * B_DIM + grow) * G_DIM + ucol;
            xc0 = xr[0]; xc1 = xr[H_DIM]; xc2 = xr[2 * H_DIM]; xc3 = xr[3 * H_DIM];
            mkc = mask[(gt + 1) * B_DIM + grow];
        }

        __syncthreads();   // shh reads done before next iter's stage writes
    }
}

// ---------------------------------------------------------------------------
// Host side. Workspace:
//   [Whb 8MiB][Wxb 8MiB][hbuf 2x256KiB u32-tagged][cst 256KiB] (pad to 1MiB)
//   [xb chunk][xg chunk]
// ---------------------------------------------------------------------------
extern "C" void kernel_launch(void* const* d_in, const int* in_sizes, int n_in,
                              void* d_out, int out_size, void* d_ws, size_t ws_size,
                              hipStream_t stream)
{
    (void)in_sizes; (void)n_in; (void)out_size;
    const float* x     = (const float*)d_in[0];  // [512][64][1024]
    const float* xmask = (const float*)d_in[1];  // [512][64]
    const float* Wx    = (const float*)d_in[2];  // [4096][1024]
    const float* bx    = (const float*)d_in[3];  // [4096]
    const float* Wh    = (const float*)d_in[4];  // [4096][1024]
    float* out = (float*)d_out;

    char* ws = (char*)d_ws;
    __bf16* Whb = (__bf16*)(ws);
    __bf16* Wxb = (__bf16*)(ws + 8388608);
    u32*    hb  = (u32*)(ws + 16777216);                 // 2 x 262144 B
    float*  cst = (float*)(ws + 16777216 + 524288);      // 262144 B
    char* dyn = ws + 16777216 + 1048576;

    long avail = (long)ws_size - (16777216L + 1048576L);
    const long per_t = (long)B_DIM * D_DIM * 2 + (long)B_DIM * G_DIM * 4;
    long Tc = avail > 0 ? avail / per_t : 2;
    if (Tc > T_DIM) Tc = T_DIM;
    Tc &= ~1L;
    if (Tc < 2) Tc = 2;

    __bf16* xb = (__bf16*)dyn;
    float*  xg = (float*)(dyn + Tc * (long)B_DIM * D_DIM * 2);

    // zero hbuf (epoch 0 == expected tag at gt=0) + cst; ONCE, before scan
    hipMemsetAsync(ws + 16777216, 0, 1048576, stream);

    {
        long nw = (long)G_DIM * D_DIM;
        int nb = (int)(nw / 8 / 256);
        f32_to_bf16_kernel<<<nb, 256, 0, stream>>>(Wx, Wxb, nw);
        f32_to_bf16_kernel<<<nb, 256, 0, stream>>>(Wh, Whb, nw);
    }

    for (int t0 = 0; t0 < T_DIM; t0 += (int)Tc) {
        int tc = (int)((T_DIM - t0 < Tc) ? (long)(T_DIM - t0) : Tc);

        long nx = (long)tc * B_DIM * D_DIM;
        f32_to_bf16_kernel<<<(int)(nx / 8 / 256), 256, 0, stream>>>(
            x + (long)t0 * B_DIM * D_DIM, xb, nx);

        dim3 gg(G_DIM / BN, (tc * B_DIM) / BM);
        gemm_xg_kernel<<<gg, 256, 0, stream>>>(xb, Wxb, bx, xg, tc * B_DIM);

        const __bf16* Whb_a = Whb;
        const float*  xg_a  = xg;
        const float*  mask_a = xmask;
        float*  cst_a = cst;
        u32*    hb_a  = hb;
        float*  out_a = out;
        int t0_a = t0, tc_a = tc;
        void* args[] = {(void*)&Whb_a, (void*)&xg_a, (void*)&mask_a,
                        (void*)&cst_a, (void*)&hb_a, (void*)&out_a,
                        (void*)&t0_a, (void*)&tc_a};
        hipLaunchCooperativeKernel((void*)lstm_scan_kernel, dim3(NWG), dim3(WGT),
                                   args, 0, stream);
    }
}

// Round 8
// 2397.186 us; speedup vs baseline: 1.3820x; 1.3820x over previous
//
#include <hip/hip_runtime.h>
#include <hip/hip_bf16.h>

using f32x4  = __attribute__((ext_vector_type(4))) float;
using bf16x8 = __attribute__((ext_vector_type(8))) __bf16;
using u64    = unsigned long long;

#define T_DIM 512
#define B_DIM 64
#define D_DIM 1024
#define H_DIM 1024
#define G_DIM 4096   // 4*H
#define NWG   128    // scan wgs: 4 row-groups x 32 unit-blocks
#define WGT   512    // threads per scan wg (8 waves)

// ---------------------------------------------------------------------------
// fp32 -> bf16 conversion (vectorized 8/thread)
// ---------------------------------------------------------------------------
__global__ void f32_to_bf16_kernel(const float* __restrict__ src,
                                   __bf16* __restrict__ dst, long n) {
    long i = ((long)blockIdx.x * blockDim.x + threadIdx.x) * 8;
    if (i + 8 <= n) {
        f32x4 a = *(const f32x4*)(src + i);
        f32x4 b = *(const f32x4*)(src + i + 4);
        bf16x8 o;
        o[0] = (__bf16)a[0]; o[1] = (__bf16)a[1];
        o[2] = (__bf16)a[2]; o[3] = (__bf16)a[3];
        o[4] = (__bf16)b[0]; o[5] = (__bf16)b[1];
        o[6] = (__bf16)b[2]; o[7] = (__bf16)b[3];
        *(bf16x8*)(dst + i) = o;
    }
}

// ---------------------------------------------------------------------------
// Phase 1: xg[M][4096] = A[M][1024](bf16) @ W[4096][1024]^T (bf16) + bias
// (unchanged)
// ---------------------------------------------------------------------------
#define BM 128
#define BN 128
#define BK 64

__global__ __launch_bounds__(256) void gemm_xg_kernel(
    const __bf16* __restrict__ A,    // [M][1024]
    const __bf16* __restrict__ W,    // [4096][1024]
    const float* __restrict__ bias,  // [4096]
    float* __restrict__ C,           // [M][4096]
    int M)
{
    (void)M;
    __shared__ __bf16 sA[BM * BK];
    __shared__ __bf16 sB[BN * BK];

    const int tid = threadIdx.x;
    const int wv  = tid >> 6;
    const int l   = tid & 63;
    const int wy  = wv >> 1, wx = wv & 1;
    const int bm  = blockIdx.y * BM;
    const int bn  = blockIdx.x * BN;
    const int n   = l & 15;
    const int q   = l >> 4;

    const int srow  = l >> 3;
    const int skoff = (l & 7) * 8;

    f32x4 acc[4][4];
    #pragma unroll
    for (int mt = 0; mt < 4; ++mt)
        #pragma unroll
        for (int nt = 0; nt < 4; ++nt)
            acc[mt][nt] = (f32x4){0.f, 0.f, 0.f, 0.f};

    for (int kt = 0; kt < D_DIM / BK; ++kt) {
        const int k0 = kt * BK;
        #pragma unroll
        for (int j = 0; j < 4; ++j) {
            const int rbase = (j * 4 + wv) * 8;
            const __bf16* ga = A + (long)(bm + rbase + srow) * D_DIM + k0 + skoff;
            const __bf16* gb = W + (long)(bn + rbase + srow) * D_DIM + k0 + skoff;
            __builtin_amdgcn_global_load_lds(
                (const __attribute__((address_space(1))) void*)ga,
                (__attribute__((address_space(3))) void*)(sA + rbase * BK), 16, 0, 0);
            __builtin_amdgcn_global_load_lds(
                (const __attribute__((address_space(1))) void*)gb,
                (__attribute__((address_space(3))) void*)(sB + rbase * BK), 16, 0, 0);
        }
        __syncthreads();

        #pragma unroll
        for (int ks = 0; ks < 2; ++ks) {
            bf16x8 af[4], bfr[4];
            #pragma unroll
            for (int mt = 0; mt < 4; ++mt) {
                int row = wy * 64 + mt * 16 + n;
                af[mt] = *(const bf16x8*)(sA + row * BK + ks * 32 + q * 8);
            }
            #pragma unroll
            for (int nt = 0; nt < 4; ++nt) {
                int col = wx * 64 + nt * 16 + n;
                bfr[nt] = *(const bf16x8*)(sB + col * BK + ks * 32 + q * 8);
            }
            #pragma unroll
            for (int mt = 0; mt < 4; ++mt)
                #pragma unroll
                for (int nt = 0; nt < 4; ++nt)
                    acc[mt][nt] = __builtin_amdgcn_mfma_f32_16x16x32_bf16(
                        af[mt], bfr[nt], acc[mt][nt], 0, 0, 0);
        }
        __syncthreads();
    }

    #pragma unroll
    for (int nt = 0; nt < 4; ++nt) {
        int col = bn + wx * 64 + nt * 16 + n;
        float b = bias[col];
        #pragma unroll
        for (int mt = 0; mt < 4; ++mt) {
            #pragma unroll
            for (int r = 0; r < 4; ++r) {
                int row = bm + wy * 64 + mt * 16 + q * 4 + r;
                C[(long)row * G_DIM + col] = acc[mt][nt][r] + b;
            }
        }
    }
}

// ---------------------------------------------------------------------------
// fast tanh via __expf. err ~1e-6, tol 1.5e-2.
// ---------------------------------------------------------------------------
__device__ __forceinline__ float fast_tanh(float x) {
    return 1.0f - 2.0f / (__expf(2.0f * x) + 1.0f);
}

// ---------------------------------------------------------------------------
// Phase 2: persistent scan (round 8 = round 5/6 protocol + drain-path fixes).
// Flag-based exchange (round-7 tag protocol REVERTED: its all-thread 16B
// retry polling was a MALL request storm, +50% step time).
// Topology (round-5/6 proven): 128 wgs = 4 row-groups x 32 unit-blocks,
// 8 waves; wave wv owns units ublk*32+wv*4..+3 x all 4 gates; fragment-major
// LDS for conflict-free ds_read_b128; intra-wave gate exchange; shfl pack.
//
// Round-8 changes (critical-path surgery only):
//  1. out-store / cst-store / xg-prefetch moved AFTER the flag publish:
//     the pre-publish __syncthreads drains vmcnt(0), so anything issued
//     before it (HBM out-stores, xg loads ~200-900cy) sat on the publish
//     path. Now only the two 8B h-stores are drained.
//  2. post-poll barrier downgraded to RAW s_barrier + compiler acquire
//     fence: its only job is broadcasting poll-success across waves. The
//     shh write(t+1)/read(t) hazard is already ordered by the pre-publish
//     full __syncthreads (all ds_reads retired there). A full __syncthreads
//     here would re-drain the just-issued out/xg ops back onto the path.
//  3. round-6 asm breg pin dropped (proven ineffective; suspected to
//     serialize per-step Wh reloads at loop top).
// ---------------------------------------------------------------------------
__global__ __launch_bounds__(WGT)
__attribute__((amdgpu_waves_per_eu(2, 2)))
void lstm_scan_kernel(
    const __bf16* __restrict__ Whb,   // [4096][1024] bf16
    const float* __restrict__ xg,     // [tc][64][4096] fp32 (chunk-local)
    const float* __restrict__ mask,   // [512][64]
    float* __restrict__ cst,          // [64][1024] fp32 chunk-boundary state
    __bf16* __restrict__ hbuf,        // [2][64][1024] bf16 state
    float* __restrict__ out,          // [512][64][1024]
    unsigned* __restrict__ flags,     // [128] flags, 64B-padded
    int t0, int tc)
{
    __shared__ __align__(16) char shh[32768];   // h rows, fragment-major
    __shared__ float sg[8][16 * 17];            // per-wave gate exchange

    const int tid  = threadIdx.x;
    const int wgid = blockIdx.x;
    const int rblk = wgid >> 5;          // row group 0..3 (rows rblk*16..+15)
    const int ublk = wgid & 31;          // unit block 0..31
    const int wv   = tid >> 6;
    const int l    = tid & 63;
    const int n    = l & 15;
    const int q    = l >> 4;

    // wave wv: units ublk*32 + wv*4..+3, all 4 gates
    const int colg = ((n >> 2) << 10) + ublk * 32 + wv * 4 + (n & 3);

    bf16x8 breg[32];
    #pragma unroll
    for (int kk = 0; kk < 32; ++kk)
        breg[kk] = *(const bf16x8*)(Whb + (long)colg * H_DIM + kk * 32 + q * 8);

    // gate-phase ownership
    const int rloc = l >> 2;                   // 0..15
    const int ui   = l & 3;                    // 0..3
    const int grow = rblk * 16 + rloc;         // global batch row
    const int ucol = ublk * 32 + wv * 4 + ui;  // global hidden unit

    // staging geometry (round-5 proven): wave wv stages kk = wv*4..wv*4+3
    const int srow_lo = (l >> 3);        // 0..7
    const int sv      = l & 7;           // u64-in-row selector
    const int sq      = (l >> 1) & 3;    // fragment q of this u64
    const int sb      = (l & 1) * 8;     // byte-in-fragment

    float c_r, h_r;
    if (t0 == 0) { c_r = 0.0f; h_r = 0.0f; }
    else {
        c_r = cst[grow * H_DIM + ucol];
        h_r = out[((long)(t0 - 1) * B_DIM + grow) * H_DIM + ucol];
    }

    // prefetch xg/mask for t = 0
    float xc0, xc1, xc2, xc3, mkc;
    {
        const float* xr = xg + (long)grow * G_DIM + ucol;
        xc0 = xr[0]; xc1 = xr[H_DIM]; xc2 = xr[2 * H_DIM]; xc3 = xr[3 * H_DIM];
        mkc = mask[t0 * B_DIM + grow];
    }

    for (int t = 0; t < tc; ++t) {
        const int gt = t0 + t;
        const __bf16* hread = hbuf + (long)(gt & 1) * (B_DIM * H_DIM);
        __bf16* hwrite = hbuf + (long)((gt + 1) & 1) * (B_DIM * H_DIM);
        const u64* h64 = (const u64*)hread;

        // ---- stage: 8 coherent loads (one burst), fragment-major LDS ----
        u64 hold[8];
        #pragma unroll
        for (int j = 0; j < 4; ++j) {
            const int kk = wv * 4 + j;
            hold[j * 2]     = __hip_atomic_load(
                h64 + (long)(rblk * 16 + srow_lo) * 256 + kk * 8 + sv,
                __ATOMIC_RELAXED, __HIP_MEMORY_SCOPE_AGENT);
            hold[j * 2 + 1] = __hip_atomic_load(
                h64 + (long)(rblk * 16 + 8 + srow_lo) * 256 + kk * 8 + sv,
                __ATOMIC_RELAXED, __HIP_MEMORY_SCOPE_AGENT);
        }
        #pragma unroll
        for (int j = 0; j < 4; ++j) {
            const int kk = wv * 4 + j;
            *(u64*)(shh + kk * 1024 + sq * 256 + srow_lo * 16 + sb)       = hold[j * 2];
            *(u64*)(shh + kk * 1024 + sq * 256 + (8 + srow_lo) * 16 + sb) = hold[j * 2 + 1];
        }
        __syncthreads();   // syncA: staged h visible to all waves

        // ---- 32 MFMAs, full K, contiguous 1KB ds_read_b128 per fragment ----
        f32x4 ac0 = {0.f,0.f,0.f,0.f}, ac1 = {0.f,0.f,0.f,0.f};
        #pragma unroll
        for (int kk = 0; kk < 32; kk += 2) {
            bf16x8 f0 = *(const bf16x8*)(shh + (kk + 0) * 1024 + q * 256 + n * 16);
            bf16x8 f1 = *(const bf16x8*)(shh + (kk + 1) * 1024 + q * 256 + n * 16);
            ac0 = __builtin_amdgcn_mfma_f32_16x16x32_bf16(f0, breg[kk + 0], ac0, 0, 0, 0);
            ac1 = __builtin_amdgcn_mfma_f32_16x16x32_bf16(f1, breg[kk + 1], ac1, 0, 0, 0);
        }
        f32x4 acc = ac0 + ac1;

        // ---- intra-wave gate exchange (same-wave LDS, no barrier) ----
        #pragma unroll
        for (int r = 0; r < 4; ++r)
            sg[wv][(q * 4 + r) * 17 + n] = acc[r];

        float ig = xc0 + sg[wv][rloc * 17 + 0  + ui];
        float fg = xc1 + sg[wv][rloc * 17 + 4  + ui];
        float og = xc2 + sg[wv][rloc * 17 + 8  + ui];
        float gg = xc3 + sg[wv][rloc * 17 + 12 + ui];

        float i_s = 1.0f / (1.0f + __expf(-ig));
        float f_s = 1.0f / (1.0f + __expf(-fg));
        float o_s = 1.0f / (1.0f + __expf(-og));
        float g_t = fast_tanh(gg);
        float c_new = f_s * c_r + i_s * g_t;
        float h_new = o_s * fast_tanh(c_new);
        float c_f = mkc * c_new + (1.0f - mkc) * c_r;
        float h_f = mkc * h_new + (1.0f - mkc) * h_r;
        c_r = c_f;
        h_r = h_f;

        // ---- h store FIRST (the only thing the publish waits on) ----
        const int base = l & ~3;
        float v0 = __shfl(h_f, base + 0);
        float v1 = __shfl(h_f, base + 1);
        float v2 = __shfl(h_f, base + 2);
        float v3 = __shfl(h_f, base + 3);
        if (ui == 0) {
            unsigned short b0 = __builtin_bit_cast(unsigned short, (__bf16)v0);
            unsigned short b1 = __builtin_bit_cast(unsigned short, (__bf16)v1);
            unsigned short b2 = __builtin_bit_cast(unsigned short, (__bf16)v2);
            unsigned short b3 = __builtin_bit_cast(unsigned short, (__bf16)v3);
            u64 pk = (u64)b0 | ((u64)b1 << 16) | ((u64)b2 << 32) | ((u64)b3 << 48);
            u64* dp = (u64*)((unsigned short*)hwrite +
                             (long)grow * H_DIM + ublk * 32 + wv * 4);
            __hip_atomic_store(dp, pk, __ATOMIC_RELAXED, __HIP_MEMORY_SCOPE_AGENT);
        }

        // syncB: per-wave vmcnt(0) drains ONLY the h stores -> publish safe
        __syncthreads();
        if (tid == 0)
            __hip_atomic_store(&flags[wgid * 16], (unsigned)(gt + 1),
                               __ATOMIC_RELAXED, __HIP_MEMORY_SCOPE_AGENT);

        // ---- off-critical-path work: hidden under the poll ----
        if (ui == 0) {
            f32x4 ov = {v0, v1, v2, v3};
            *(f32x4*)(out + ((long)gt * B_DIM + grow) * H_DIM + ublk * 32 + wv * 4) = ov;
        }
        if (t == tc - 1) cst[grow * H_DIM + ucol] = c_f;
        if (t + 1 < tc) {
            const float* xr = xg + ((long)(t + 1) * B_DIM + grow) * G_DIM + ucol;
            xc0 = xr[0]; xc1 = xr[H_DIM]; xc2 = xr[2 * H_DIM]; xc3 = xr[3 * H_DIM];
            mkc = mask[(gt + 1) * B_DIM + grow];
        }

        // ---- poll own row-group's 32 flags, then RAW barrier (no drain) ----
        if (t + 1 < tc) {
            if (tid < 64) {
                const unsigned* fp = &flags[(rblk * 32 + (tid & 31)) * 16];
                const unsigned target = (unsigned)(gt + 1);
                for (;;) {
                    unsigned v = __hip_atomic_load(fp, __ATOMIC_RELAXED,
                                                   __HIP_MEMORY_SCOPE_AGENT);
                    if (__all(v >= target)) break;
                    __builtin_amdgcn_s_sleep(1);
                }
            }
            __builtin_amdgcn_s_barrier();               // syncC: broadcast only
            __atomic_signal_fence(__ATOMIC_ACQUIRE);    // keep h loads after poll
        }
    }
}

// ---------------------------------------------------------------------------
// Host side. Workspace:
//   [Whb 8MiB][Wxb 8MiB][hbuf 2x128KiB][cst 256KiB][flags 8KiB pad-64B]
//   (pad to 1MiB) [xb chunk][xg chunk]
// ---------------------------------------------------------------------------
extern "C" void kernel_launch(void* const* d_in, const int* in_sizes, int n_in,
                              void* d_out, int out_size, void* d_ws, size_t ws_size,
                              hipStream_t stream)
{
    (void)in_sizes; (void)n_in; (void)out_size;
    const float* x     = (const float*)d_in[0];  // [512][64][1024]
    const float* xmask = (const float*)d_in[1];  // [512][64]
    const float* Wx    = (const float*)d_in[2];  // [4096][1024]
    const float* bx    = (const float*)d_in[3];  // [4096]
    const float* Wh    = (const float*)d_in[4];  // [4096][1024]
    float* out = (float*)d_out;

    char* ws = (char*)d_ws;
    __bf16*   Whb   = (__bf16*)(ws);
    __bf16*   Wxb   = (__bf16*)(ws + 8388608);
    __bf16*   hb    = (__bf16*)(ws + 16777216);             // 2 x 131072 B
    float*    cst   = (float*)(ws + 16777216 + 262144);     // 262144 B
    unsigned* flags = (unsigned*)(ws + 16777216 + 524288);  // 8192 B (64B-padded)
    char* dyn = ws + 16777216 + 1048576;

    long avail = (long)ws_size - (16777216L + 1048576L);
    const long per_t = (long)B_DIM * D_DIM * 2 + (long)B_DIM * G_DIM * 4;
    long Tc = avail > 0 ? avail / per_t : 2;
    if (Tc > T_DIM) Tc = T_DIM;
    Tc &= ~1L;
    if (Tc < 2) Tc = 2;

    __bf16* xb = (__bf16*)dyn;
    float*  xg = (float*)(dyn + Tc * (long)B_DIM * D_DIM * 2);

    // zero h0 state + barrier flags (once, before the chunk loop)
    hipMemsetAsync(ws + 16777216, 0, 1048576, stream);

    {
        long nw = (long)G_DIM * D_DIM;
        int nb = (int)(nw / 8 / 256);
        f32_to_bf16_kernel<<<nb, 256, 0, stream>>>(Wx, Wxb, nw);
        f32_to_bf16_kernel<<<nb, 256, 0, stream>>>(Wh, Whb, nw);
    }

    for (int t0 = 0; t0 < T_DIM; t0 += (int)Tc) {
        int tc = (int)((T_DIM - t0 < Tc) ? (long)(T_DIM - t0) : Tc);

        long nx = (long)tc * B_DIM * D_DIM;
        f32_to_bf16_kernel<<<(int)(nx / 8 / 256), 256, 0, stream>>>(
            x + (long)t0 * B_DIM * D_DIM, xb, nx);

        dim3 gg(G_DIM / BN, (tc * B_DIM) / BM);
        gemm_xg_kernel<<<gg, 256, 0, stream>>>(xb, Wxb, bx, xg, tc * B_DIM);

        const __bf16* Whb_a = Whb;
        const float*  xg_a  = xg;
        const float*  mask_a = xmask;
        float*  cst_a = cst;
        __bf16* hb_a  = hb;
        float*  out_a = out;
        unsigned* fl_a = flags;
        int t0_a = t0, tc_a = tc;
        void* args[] = {(void*)&Whb_a, (void*)&xg_a, (void*)&mask_a,
                        (void*)&cst_a, (void*)&hb_a, (void*)&out_a,
                        (void*)&fl_a, (void*)&t0_a, (void*)&tc_a};
        hipLaunchCooperativeKernel((void*)lstm_scan_kernel, dim3(NWG), dim3(WGT),
                                   args, 0, stream);
    }
}